// Round 14
// baseline (829.867 us; speedup 1.0000x reference)
//
#include <hip/hip_runtime.h>
#include <hip/hip_bf16.h>
#include <stdint.h>

#define M_DIM 8192
#define K_DIM 4096
#define N_DIM 11008

typedef __attribute__((ext_vector_type(8))) short bf16x8;
typedef __attribute__((ext_vector_type(4))) float f32x4;
typedef __attribute__((ext_vector_type(4))) unsigned int uint4v;

__device__ __forceinline__ unsigned short f2bf(float f) {
    __hip_bfloat16 h = __float2bfloat16(f);
    return __builtin_bit_cast(unsigned short, h);
}

__device__ __forceinline__ void gload_lds16(const unsigned short* g, unsigned short* l) {
    __builtin_amdgcn_global_load_lds(
        (const __attribute__((address_space(1))) void*)g,
        (__attribute__((address_space(3))) void*)l,
        16, 0, 0);
}

__device__ __forceinline__ unsigned lds_addr(const unsigned short* p) {
    return (unsigned)(uintptr_t)(const __attribute__((address_space(3))) unsigned short*)p;
}

// inline-asm ds_read_b128 with immediate offset; hand-placed counted lgkm
// waits order the consumers.
#define DSRI(dst, a, OFF) asm volatile("ds_read_b128 %0, %1 offset:%2" \
    : "=v"(dst) : "v"(a), "n"(OFF) : "memory")

// counted lgkm wait + scheduler fence (rule #18).
#define LGKM(N) do { \
    asm volatile("s_waitcnt lgkmcnt(" #N ")" ::: "memory"); \
    __builtin_amdgcn_sched_barrier(0); \
} while (0)
#define VMC(N) asm volatile("s_waitcnt vmcnt(" #N ")" ::: "memory")
#define BAR() do { __builtin_amdgcn_s_barrier(); asm volatile("" ::: "memory"); } while (0)

// ---------------------------------------------------------------------------
// Kernel 1: fused column-gather + fp32->bf16 convert.
// ---------------------------------------------------------------------------
__global__ void permute_x_kernel(const float* __restrict__ x,
                                 const int* __restrict__ ci,
                                 unsigned short* __restrict__ xg) {
    int idx = blockIdx.x * 256 + threadIdx.x;
    int64_t base = (int64_t)idx * 4;
    int m = (int)(base >> 12);        // K=4096
    int k = (int)(base & 4095);
    const float* xrow = x + ((int64_t)m << 12);
    int4 c4 = *reinterpret_cast<const int4*>(ci + k);
    ushort4 o;
    o.x = f2bf(xrow[c4.x]);
    o.y = f2bf(xrow[c4.y]);
    o.z = f2bf(xrow[c4.z]);
    o.w = f2bf(xrow[c4.w]);
    *reinterpret_cast<ushort4*>(xg + base) = o;
}

// ---------------------------------------------------------------------------
// Kernel 2: int4 unpack + per-group scale + transpose to wT[N][K] bf16.
// ---------------------------------------------------------------------------
__global__ void dequant_w_kernel(const int* __restrict__ wp,
                                 const float* __restrict__ scales,
                                 unsigned short* __restrict__ wT) {
    __shared__ unsigned short tile[64][65];
    int n0 = blockIdx.x * 64;
    int k0 = blockIdx.y * 64;
    int g = k0 >> 7;
    int t = threadIdx.x;
    int col = t & 63;
    int r0 = t >> 6;
    float s = scales[(int64_t)g * N_DIM + n0 + col];
    int pr0 = k0 >> 1;
#pragma unroll
    for (int i = 0; i < 8; ++i) {
        int row = r0 + i * 4;
        int p = wp[(int64_t)(pr0 + row) * N_DIM + n0 + col];
        tile[2 * row][col]     = f2bf((float)((p & 15) - 8) * s);
        tile[2 * row + 1][col] = f2bf((float)(((p >> 4) & 15) - 8) * s);
    }
    __syncthreads();
    int nl = t >> 2;
    int kk0 = (t & 3) << 4;
    unsigned short vals[16];
#pragma unroll
    for (int j = 0; j < 16; ++j) vals[j] = tile[kk0 + j][nl];
    uint4v* dst = reinterpret_cast<uint4v*>(wT + (int64_t)(n0 + nl) * K_DIM + k0 + kk0);
    dst[0] = *reinterpret_cast<const uint4v*>(&vals[0]);
    dst[1] = *reinterpret_cast<const uint4v*>(&vals[8]);
}

// ---------------------------------------------------------------------------
// Kernel 3: bf16 GEMM = round-13 kernel (256x256, BK=32, 16x16x32, 4-buffer
// rotation, vmcnt(6), 0 bank conflicts) + s_setprio(1/0) around each MFMA
// cluster (T5, this round's ONLY change — unbundling the r13 removal).
//
// Rationale: r13 wall = MFMA(1242) + LDS-port(~1024) nearly SUMMED per tile
// (2512 cyc measured) — barrier-lockstep burst alternation. T5's measured
// +21-25% (m218b) applies to phase-split schedules with counted waits =
// exactly this structure; m190's null was on the single-phase m97 structure.
//
// Schedule per K-tile j (buf B=j%4, BN=(j+1)%4, BS=(j+3)%4):
//  P1: issue RB_j (4 ds: A m4-7); stage A_{j+3}->BS; LGKM(4) [drains RA_j];
//      setprio1 16 MFMA (m0-3) setprio0; vmcnt(6); BAR.
//  P2: issue RA_{j+1} (8 ds: A m0-3 + B n0-3 of buf BN); stage B_{j+3};
//      LGKM(8) [drains RB_j]; setprio1 16 MFMA (m4-7) setprio0; BAR.
// Ledgers identical to r13 (see r13 comments; re-verified unchanged).
// ---------------------------------------------------------------------------

template <int BUF>
__device__ __forceinline__ void read_RA(bf16x8 (&a)[4], bf16x8 (&b)[4],
                                        unsigned aA01, unsigned aA23,
                                        unsigned bB01, unsigned bB23) {
    const unsigned ad = (BUF < 2) ? aA01 : aA23;
    const unsigned bd = (BUF < 2) ? bB01 : bB23;
    constexpr int bo = (BUF & 1) * 32768;
    DSRI(a[0], ad, bo + 0);
    DSRI(a[1], ad, bo + 1024);
    DSRI(a[2], ad, bo + 2048);
    DSRI(a[3], ad, bo + 3072);
    DSRI(b[0], bd, bo + 0);
    DSRI(b[1], bd, bo + 1024);
    DSRI(b[2], bd, bo + 2048);
    DSRI(b[3], bd, bo + 3072);
}

template <int BUF>
__device__ __forceinline__ void read_RB(bf16x8 (&a2)[4], unsigned aA01, unsigned aA23) {
    const unsigned ad = (BUF < 2) ? aA01 : aA23;
    constexpr int bo = (BUF & 1) * 32768;
    DSRI(a2[0], ad, bo + 4096);
    DSRI(a2[1], ad, bo + 5120);
    DSRI(a2[2], ad, bo + 6144);
    DSRI(a2[3], ad, bo + 7168);
}

template <int MB>
__device__ __forceinline__ void mfma4(f32x4 (&acc)[8][4], const bf16x8 (&av)[4],
                                      const bf16x8 (&bv)[4]) {
    __builtin_amdgcn_s_setprio(1);
#pragma unroll
    for (int m = 0; m < 4; ++m)
#pragma unroll
        for (int n = 0; n < 4; ++n)
            acc[MB + m][n] = __builtin_amdgcn_mfma_f32_16x16x32_bf16(
                av[m], bv[n], acc[MB + m][n], 0, 0, 0);
    __builtin_amdgcn_s_setprio(0);
}

// stage one 16 KiB region (256 rows x 32 k) of K-tile t into buf DBUF.
template <int DBUF, int ISB>
__device__ __forceinline__ void stage2(const unsigned short* p0, const unsigned short* p1,
                                       int t, unsigned short* lds, int wLds) {
    const unsigned short* s0 = p0 + t * 32;
    const unsigned short* s1 = p1 + t * 32;
    unsigned short* d = lds + DBUF * 16384 + ISB * 8192 + wLds;
    gload_lds16(s0, d);
    gload_lds16(s1, d + 512);
}

// one K-tile: B=buf j%4, BN=(j+1)%4, BS=(j+3)%4; CA_/CB_ = consume color
// frags (tile j), NA_/NB_ = next color frags (tile j+1); tt = j+3.
#define PH_TILE(B, BN, BS, CA_, CB_, NA_, NB_, tt)                        \
    do {                                                                  \
        read_RB<B>(a2, aA01, aA23);                                       \
        stage2<BS, 0>(pA0, pA1, (tt), lds, wLds);                         \
        LGKM(4);                                                          \
        mfma4<0>(acc, CA_, CB_);                                          \
        VMC(6);                                                           \
        BAR();                                                            \
        read_RA<BN>(NA_, NB_, aA01, aA23, bB01, bB23);                    \
        stage2<BS, 1>(pB0, pB1, (tt), lds, wLds);                         \
        LGKM(8);                                                          \
        mfma4<4>(acc, a2, CB_);                                           \
        BAR();                                                            \
    } while (0)

__global__ __launch_bounds__(512, 2)
void gemm_kernel(const unsigned short* __restrict__ A,
                 const unsigned short* __restrict__ BT,
                 const float* __restrict__ bias,
                 float* __restrict__ C) {
    __shared__ unsigned short lds[65536];   // 128 KiB: 4 bufs x 32 KiB

    constexpr int NT = N_DIM / 256;  // 43
    int wg = blockIdx.x, nwg = gridDim.x;
    int q = nwg >> 3, r = nwg & 7;
    int xcd = wg & 7, li = wg >> 3;
    int swz = (xcd < r ? xcd * (q + 1) : r * (q + 1) + (xcd - r) * q) + li;
    int by = swz / NT, bx = swz - by * NT;
    int brow = by << 8, bcol = bx << 8;

    int t = threadIdx.x;
    int lane = t & 63, w = t >> 6;
    int wr = w >> 2, wc = w & 3;           // 2 x 4 wave grid
    int fr = lane & 15, fq = lane >> 4;

    // T2 bank swizzle (r5, measured 0 conflicts): read XOR on byte bits 4-5;
    // inverse source col perm on staging.
    const unsigned xr = (unsigned)((fr & 6) << 3);
    const int riw = lane >> 2;
    const int s8 = ((lane & 3) ^ ((lane >> 3) & 3)) << 3;
    const int w32 = w * 32, wLds = w * 1024;

    const unsigned ldsB = lds_addr(lds);
    const unsigned aA01 = ldsB + ((unsigned)((wr * 128 + fr) * 64 + fq * 16) ^ xr);
    const unsigned bB01 = ldsB + 16384u + ((unsigned)((wc * 64 + fr) * 64 + fq * 16) ^ xr);
    const unsigned aA23 = aA01 + 65536;
    const unsigned bB23 = bB01 + 65536;

    // staging source pointers (row slice fixed per thread; k via t*32)
    const unsigned short* pA0 = A + (int64_t)(brow + w32 + riw) * K_DIM + s8;
    const unsigned short* pA1 = pA0 + 16 * K_DIM;
    const unsigned short* pB0 = BT + (int64_t)(bcol + w32 + riw) * K_DIM + s8;
    const unsigned short* pB1 = pB0 + 16 * K_DIM;

    f32x4 acc[8][4];
#pragma unroll
    for (int m = 0; m < 8; ++m)
#pragma unroll
        for (int n = 0; n < 4; ++n) acc[m][n] = (f32x4){0.f, 0.f, 0.f, 0.f};

    bf16x8 aX[4], bX[4], aY[4], bY[4], a2[4];

    // ---- prologue: stage tiles 0,1,2 -> bufs 0,1,2 (12 gloads); vmcnt(8)
    // confirms tile 0 (leaves {A1,B1,A2,B2}=8 = steady state); pre-issue
    // RA_0 (color X).
    stage2<0, 0>(pA0, pA1, 0, lds, wLds);
    stage2<0, 1>(pB0, pB1, 0, lds, wLds);
    stage2<1, 0>(pA0, pA1, 1, lds, wLds);
    stage2<1, 1>(pB0, pB1, 1, lds, wLds);
    stage2<2, 0>(pA0, pA1, 2, lds, wLds);
    stage2<2, 1>(pB0, pB1, 2, lds, wLds);
    VMC(8);
    BAR();
    read_RA<0>(aX, bX, aA01, aA23, bB01, bB23);

    // main loop: 31 bodies x 4 tiles = tiles 0..123 (stages reach tile 126).
#pragma unroll 1
    for (int body = 0; body < 31; ++body) {
        const int t3 = body * 4 + 3;
        PH_TILE(0, 1, 3, aX, bX, aY, bY, t3);       // tile 4b+0 (X -> Y)
        PH_TILE(1, 2, 0, aY, bY, aX, bX, t3 + 1);   // tile 4b+1 (Y -> X)
        PH_TILE(2, 3, 1, aX, bX, aY, bY, t3 + 2);   // tile 4b+2 (X -> Y)
        PH_TILE(3, 0, 2, aY, bY, aX, bX, t3 + 3);   // tile 4b+3 (Y -> X)
    }

    // ---- tail ----
    // tile 124 (buf 0, X): normal macro, stages tile 127 into buf 3.
    PH_TILE(0, 1, 3, aX, bX, aY, bY, 127);
    // tile 125 (buf 1, Y): no stage; vmcnt(4) confirms buf 126.
    read_RB<1>(a2, aA01, aA23);
    LGKM(4);
    mfma4<0>(acc, aY, bY);
    VMC(4);
    BAR();
    read_RA<2>(aX, bX, aA01, aA23, bB01, bB23);
    LGKM(8);
    mfma4<4>(acc, a2, bY);
    BAR();
    // tile 126 (buf 2, X): no stage; vmcnt(0) confirms buf 127.
    read_RB<2>(a2, aA01, aA23);
    LGKM(4);
    mfma4<0>(acc, aX, bX);
    VMC(0);
    BAR();
    read_RA<3>(aY, bY, aA01, aA23, bB01, bB23);
    LGKM(8);
    mfma4<4>(acc, a2, bX);
    BAR();
    // tile 127 (buf 3, Y): final.
    read_RB<3>(a2, aA01, aA23);
    LGKM(4);
    mfma4<0>(acc, aY, bY);
    LGKM(0);
    mfma4<4>(acc, a2, bY);

    // ---- epilogue: 16x16 C/D layout col=lane&15, row=(lane>>4)*4+reg ----
    int orow0 = brow + wr * 128 + fq * 4;
    int ocol0 = bcol + wc * 64 + fr;
#pragma unroll
    for (int n = 0; n < 4; ++n) {
        int col = ocol0 + n * 16;
        float bval = bias[col];
#pragma unroll
        for (int m = 0; m < 8; ++m) {
            int row = orow0 + m * 16;
            float* cp = C + (int64_t)row * N_DIM + col;
#pragma unroll
            for (int j = 0; j < 4; ++j) {
                cp[(int64_t)j * N_DIM] = acc[m][n][j] + bval;
            }
        }
    }
}

extern "C" void kernel_launch(void* const* d_in, const int* in_sizes, int n_in,
                              void* d_out, int out_size, void* d_ws, size_t ws_size,
                              hipStream_t stream) {
    const float* x      = (const float*)d_in[0];
    const int* ci       = (const int*)d_in[1];
    const int* wp       = (const int*)d_in[2];
    const float* scales = (const float*)d_in[3];
    const float* bias   = (const float*)d_in[4];
    float* out          = (float*)d_out;

    const size_t wT_bytes = (size_t)N_DIM * K_DIM * 2;
    unsigned short* wT = (unsigned short*)d_ws;
    unsigned short* xg = wT + (size_t)N_DIM * K_DIM;

    size_t cap = (ws_size > wT_bytes) ? (ws_size - wT_bytes) : 0;
    int max_rows = (int)(cap / ((size_t)K_DIM * 2));
    int chunk_rows = (max_rows / 256) * 256;
    if (chunk_rows <= 0) chunk_rows = 256;      // best effort
    if (chunk_rows > M_DIM) chunk_rows = M_DIM;

    dequant_w_kernel<<<dim3(N_DIM / 64, K_DIM / 64), 256, 0, stream>>>(wp, scales, wT);

    for (int m0 = 0; m0 < M_DIM; m0 += chunk_rows) {
        int rows = M_DIM - m0 < chunk_rows ? M_DIM - m0 : chunk_rows;
        int pgrid = (int)(((int64_t)rows * K_DIM) / (4 * 256));
        permute_x_kernel<<<pgrid, 256, 0, stream>>>(
            x + (int64_t)m0 * K_DIM, ci, xg);
        int grid = (rows / 256) * (N_DIM / 256);
        gemm_kernel<<<grid, 512, 0, stream>>>(
            xg, wT, bias, out + (int64_t)m0 * N_DIM);
    }
}

// Round 15
// 809.197 us; speedup vs baseline: 1.0255x; 1.0255x over previous
//
#include <hip/hip_runtime.h>
#include <hip/hip_bf16.h>
#include <stdint.h>

#define M_DIM 8192
#define K_DIM 4096
#define N_DIM 11008

typedef __attribute__((ext_vector_type(8))) short bf16x8;
typedef __attribute__((ext_vector_type(4))) float f32x4;
typedef __attribute__((ext_vector_type(4))) unsigned int uint4v;

__device__ __forceinline__ unsigned short f2bf(float f) {
    __hip_bfloat16 h = __float2bfloat16(f);
    return __builtin_bit_cast(unsigned short, h);
}

__device__ __forceinline__ void gload_lds16(const unsigned short* g, unsigned short* l) {
    __builtin_amdgcn_global_load_lds(
        (const __attribute__((address_space(1))) void*)g,
        (__attribute__((address_space(3))) void*)l,
        16, 0, 0);
}

__device__ __forceinline__ unsigned lds_addr(const unsigned short* p) {
    return (unsigned)(uintptr_t)(const __attribute__((address_space(3))) unsigned short*)p;
}

// inline-asm ds_read_b128 with immediate offset; hand-placed counted lgkm
// waits order the consumers.
#define DSRI(dst, a, OFF) asm volatile("ds_read_b128 %0, %1 offset:%2" \
    : "=v"(dst) : "v"(a), "n"(OFF) : "memory")

// counted lgkm wait + scheduler fence (rule #18: register-only MFMA would
// otherwise hoist above the wait).
#define LGKM(N) do { \
    asm volatile("s_waitcnt lgkmcnt(" #N ")" ::: "memory"); \
    __builtin_amdgcn_sched_barrier(0); \
} while (0)
#define VMC(N) asm volatile("s_waitcnt vmcnt(" #N ")" ::: "memory")
#define BAR() do { __builtin_amdgcn_s_barrier(); asm volatile("" ::: "memory"); } while (0)

// ---------------------------------------------------------------------------
// Kernel 1: fused column-gather + fp32->bf16 convert.
// ---------------------------------------------------------------------------
__global__ void permute_x_kernel(const float* __restrict__ x,
                                 const int* __restrict__ ci,
                                 unsigned short* __restrict__ xg) {
    int idx = blockIdx.x * 256 + threadIdx.x;
    int64_t base = (int64_t)idx * 4;
    int m = (int)(base >> 12);        // K=4096
    int k = (int)(base & 4095);
    const float* xrow = x + ((int64_t)m << 12);
    int4 c4 = *reinterpret_cast<const int4*>(ci + k);
    ushort4 o;
    o.x = f2bf(xrow[c4.x]);
    o.y = f2bf(xrow[c4.y]);
    o.z = f2bf(xrow[c4.z]);
    o.w = f2bf(xrow[c4.w]);
    *reinterpret_cast<ushort4*>(xg + base) = o;
}

// ---------------------------------------------------------------------------
// Kernel 2: int4 unpack + per-group scale + transpose to wT[N][K] bf16.
// ---------------------------------------------------------------------------
__global__ void dequant_w_kernel(const int* __restrict__ wp,
                                 const float* __restrict__ scales,
                                 unsigned short* __restrict__ wT) {
    __shared__ unsigned short tile[64][65];
    int n0 = blockIdx.x * 64;
    int k0 = blockIdx.y * 64;
    int g = k0 >> 7;
    int t = threadIdx.x;
    int col = t & 63;
    int r0 = t >> 6;
    float s = scales[(int64_t)g * N_DIM + n0 + col];
    int pr0 = k0 >> 1;
#pragma unroll
    for (int i = 0; i < 8; ++i) {
        int row = r0 + i * 4;
        int p = wp[(int64_t)(pr0 + row) * N_DIM + n0 + col];
        tile[2 * row][col]     = f2bf((float)((p & 15) - 8) * s);
        tile[2 * row + 1][col] = f2bf((float)(((p >> 4) & 15) - 8) * s);
    }
    __syncthreads();
    int nl = t >> 2;
    int kk0 = (t & 3) << 4;
    unsigned short vals[16];
#pragma unroll
    for (int j = 0; j < 16; ++j) vals[j] = tile[kk0 + j][nl];
    uint4v* dst = reinterpret_cast<uint4v*>(wT + (int64_t)(n0 + nl) * K_DIM + k0 + kk0);
    dst[0] = *reinterpret_cast<const uint4v*>(&vals[0]);
    dst[1] = *reinterpret_cast<const uint4v*>(&vals[8]);
}

// ---------------------------------------------------------------------------
// Kernel 3: bf16 GEMM = round-13 base (256x256, BK=32, 16x16x32, 4-buffer
// ring, vmcnt(6), 0 bank conflicts, no setprio) + BALANCED 6/6 READ SPLIT
// with quadrant MFMA clusters (this round's only change).
//
// Stall model (r13 counters): wall 2491 cyc/tile = MFMA 1242 + DS 1440
// poorly overlapped because reads were 4 (P1) / 8 (P2): P2's 64-read burst
// (~770 cyc CU backlog) spills into next P1's LGKM. Rebalance:
//   R1_j = {A m0-3 (4), B n0-1 (2)}  issued P2(j-1)   [6 reads]
//   R2_j = {A m4-7 (4), B n2-3 (2)}  issued P1(j)     [6 reads]
// MFMA quadrants: c1 = m0-3 x n0-1 (R1), c2 = m4-7 x n0-1 (+R2),
//                 c3 = m0-3 x n2-3, c4 = m4-7 x n2-3 (all-resident).
//
// Per tile j (buf B=j%4, BN=(j+1)%4, BS=(j+3)%4):
//  P1: issue R2_j; stage A_{j+3}; LGKM(6) [queue R1_j(6)+R2_j(6) -> R1 done];
//      c1; LGKM(0) [R2 done, covered by c1]; c2; VMC(6); BAR.
//  P2: issue R1_{j+1} (buf BN, published end-P1(j)); stage B_{j+3};
//      c3; c4 [operands fully register-resident -> zero waits]; BAR.
//
// Ledgers: reads of buf i all after its publish barrier (end P1(i-1)); R2_i
// drained at LGKM(0)@P1(i), >=2 barriers before buf i%4 re-staged @P1(i+1);
// vmcnt ledger identical to r13 (4 gloads/tile; VMC(6) leaves {A,B}_{j+2}
// + A_{j+3}; tail VMC 4/0). Frag regs: R1 x2 colors (12) + R2 x1 (6) = 72.
// ---------------------------------------------------------------------------

template <int BUF>
__device__ __forceinline__ void read_R1(bf16x8 (&a03)[4], bf16x8 (&b01)[2],
                                        unsigned aA01, unsigned aA23,
                                        unsigned bB01, unsigned bB23) {
    const unsigned ad = (BUF < 2) ? aA01 : aA23;
    const unsigned bd = (BUF < 2) ? bB01 : bB23;
    constexpr int bo = (BUF & 1) * 32768;
    DSRI(a03[0], ad, bo + 0);
    DSRI(a03[1], ad, bo + 1024);
    DSRI(a03[2], ad, bo + 2048);
    DSRI(a03[3], ad, bo + 3072);
    DSRI(b01[0], bd, bo + 0);
    DSRI(b01[1], bd, bo + 1024);
}

template <int BUF>
__device__ __forceinline__ void read_R2(bf16x8 (&a47)[4], bf16x8 (&b23)[2],
                                        unsigned aA01, unsigned aA23,
                                        unsigned bB01, unsigned bB23) {
    const unsigned ad = (BUF < 2) ? aA01 : aA23;
    const unsigned bd = (BUF < 2) ? bB01 : bB23;
    constexpr int bo = (BUF & 1) * 32768;
    DSRI(a47[0], ad, bo + 4096);
    DSRI(a47[1], ad, bo + 5120);
    DSRI(a47[2], ad, bo + 6144);
    DSRI(a47[3], ad, bo + 7168);
    DSRI(b23[0], bd, bo + 2048);
    DSRI(b23[1], bd, bo + 3072);
}

// 8 MFMA: rows MB..MB+3 x cols NB..NB+1.
template <int MB, int NB>
__device__ __forceinline__ void mfma8(f32x4 (&acc)[8][4], const bf16x8 (&av)[4],
                                      const bf16x8 (&bv)[2]) {
#pragma unroll
    for (int m = 0; m < 4; ++m)
#pragma unroll
        for (int n = 0; n < 2; ++n)
            acc[MB + m][NB + n] = __builtin_amdgcn_mfma_f32_16x16x32_bf16(
                av[m], bv[n], acc[MB + m][NB + n], 0, 0, 0);
}

// stage one 16 KiB region (256 rows x 32 k) of K-tile t into buf DBUF.
template <int DBUF, int ISB>
__device__ __forceinline__ void stage2(const unsigned short* p0, const unsigned short* p1,
                                       int t, unsigned short* lds, int wLds) {
    const unsigned short* s0 = p0 + t * 32;
    const unsigned short* s1 = p1 + t * 32;
    unsigned short* d = lds + DBUF * 16384 + ISB * 8192 + wLds;
    gload_lds16(s0, d);
    gload_lds16(s1, d + 512);
}

// one K-tile: B=buf j%4, BN=(j+1)%4, BS=(j+3)%4; A1_/B1_ = R1_j frags
// (issued previous phase); NA1_/NB1_ = R1_{j+1} targets; tt = j+3.
#define PH_TILE(B, BN, BS, A1_, B1_, NA1_, NB1_, tt)                      \
    do {                                                                  \
        read_R2<B>(a2, b2, aA01, aA23, bB01, bB23);                       \
        stage2<BS, 0>(pA0, pA1, (tt), lds, wLds);                         \
        LGKM(6);                                                          \
        mfma8<0, 0>(acc, A1_, B1_);                                       \
        LGKM(0);                                                          \
        mfma8<4, 0>(acc, a2, B1_);                                        \
        VMC(6);                                                           \
        BAR();                                                            \
        read_R1<BN>(NA1_, NB1_, aA01, aA23, bB01, bB23);                  \
        stage2<BS, 1>(pB0, pB1, (tt), lds, wLds);                         \
        mfma8<0, 2>(acc, A1_, b2);                                        \
        mfma8<4, 2>(acc, a2, b2);                                         \
        BAR();                                                            \
    } while (0)

__global__ __launch_bounds__(512, 2)
void gemm_kernel(const unsigned short* __restrict__ A,
                 const unsigned short* __restrict__ BT,
                 const float* __restrict__ bias,
                 float* __restrict__ C) {
    __shared__ unsigned short lds[65536];   // 128 KiB: 4 bufs x 32 KiB

    constexpr int NT = N_DIM / 256;  // 43
    int wg = blockIdx.x, nwg = gridDim.x;
    int q = nwg >> 3, r = nwg & 7;
    int xcd = wg & 7, li = wg >> 3;
    int swz = (xcd < r ? xcd * (q + 1) : r * (q + 1) + (xcd - r) * q) + li;
    int by = swz / NT, bx = swz - by * NT;
    int brow = by << 8, bcol = bx << 8;

    int t = threadIdx.x;
    int lane = t & 63, w = t >> 6;
    int wr = w >> 2, wc = w & 3;           // 2 x 4 wave grid
    int fr = lane & 15, fq = lane >> 4;

    // T2 bank swizzle (r5, measured 0 conflicts): read XOR on byte bits 4-5;
    // inverse source col perm on staging.
    const unsigned xr = (unsigned)((fr & 6) << 3);
    const int riw = lane >> 2;
    const int s8 = ((lane & 3) ^ ((lane >> 3) & 3)) << 3;
    const int w32 = w * 32, wLds = w * 1024;

    const unsigned ldsB = lds_addr(lds);
    const unsigned aA01 = ldsB + ((unsigned)((wr * 128 + fr) * 64 + fq * 16) ^ xr);
    const unsigned bB01 = ldsB + 16384u + ((unsigned)((wc * 64 + fr) * 64 + fq * 16) ^ xr);
    const unsigned aA23 = aA01 + 65536;
    const unsigned bB23 = bB01 + 65536;

    // staging source pointers (row slice fixed per thread; k via t*32)
    const unsigned short* pA0 = A + (int64_t)(brow + w32 + riw) * K_DIM + s8;
    const unsigned short* pA1 = pA0 + 16 * K_DIM;
    const unsigned short* pB0 = BT + (int64_t)(bcol + w32 + riw) * K_DIM + s8;
    const unsigned short* pB1 = pB0 + 16 * K_DIM;

    f32x4 acc[8][4];
#pragma unroll
    for (int m = 0; m < 8; ++m)
#pragma unroll
        for (int n = 0; n < 4; ++n) acc[m][n] = (f32x4){0.f, 0.f, 0.f, 0.f};

    bf16x8 aX[4], bX[2], aY[4], bY[2], a2[4], b2[2];

    // ---- prologue: stage tiles 0,1,2 -> bufs 0,1,2 (12 gloads); vmcnt(8)
    // confirms tile 0 (leaves {A1,B1,A2,B2}=8 = steady state); pre-issue
    // R1_0 (color X).
    stage2<0, 0>(pA0, pA1, 0, lds, wLds);
    stage2<0, 1>(pB0, pB1, 0, lds, wLds);
    stage2<1, 0>(pA0, pA1, 1, lds, wLds);
    stage2<1, 1>(pB0, pB1, 1, lds, wLds);
    stage2<2, 0>(pA0, pA1, 2, lds, wLds);
    stage2<2, 1>(pB0, pB1, 2, lds, wLds);
    VMC(8);
    BAR();
    read_R1<0>(aX, bX, aA01, aA23, bB01, bB23);

    // main loop: 31 bodies x 4 tiles = tiles 0..123 (stages reach tile 126).
#pragma unroll 1
    for (int body = 0; body < 31; ++body) {
        const int t3 = body * 4 + 3;
        PH_TILE(0, 1, 3, aX, bX, aY, bY, t3);       // tile 4b+0 (X -> Y)
        PH_TILE(1, 2, 0, aY, bY, aX, bX, t3 + 1);   // tile 4b+1 (Y -> X)
        PH_TILE(2, 3, 1, aX, bX, aY, bY, t3 + 2);   // tile 4b+2 (X -> Y)
        PH_TILE(3, 0, 2, aY, bY, aX, bX, t3 + 3);   // tile 4b+3 (Y -> X)
    }

    // ---- tail ----
    // tile 124 (buf 0, X): normal macro, stages tile 127 into buf 3.
    PH_TILE(0, 1, 3, aX, bX, aY, bY, 127);
    // tile 125 (buf 1, Y): no stage; VMC(4) confirms buf 126.
    read_R2<1>(a2, b2, aA01, aA23, bB01, bB23);
    LGKM(6);
    mfma8<0, 0>(acc, aY, bY);
    LGKM(0);
    mfma8<4, 0>(acc, a2, bY);
    VMC(4);
    BAR();
    read_R1<2>(aX, bX, aA01, aA23, bB01, bB23);
    mfma8<0, 2>(acc, aY, b2);
    mfma8<4, 2>(acc, a2, b2);
    BAR();
    // tile 126 (buf 2, X): no stage; VMC(0) confirms buf 127.
    read_R2<2>(a2, b2, aA01, aA23, bB01, bB23);
    LGKM(6);
    mfma8<0, 0>(acc, aX, bX);
    LGKM(0);
    mfma8<4, 0>(acc, a2, bX);
    VMC(0);
    BAR();
    read_R1<3>(aY, bY, aA01, aA23, bB01, bB23);
    mfma8<0, 2>(acc, aX, b2);
    mfma8<4, 2>(acc, a2, b2);
    BAR();
    // tile 127 (buf 3, Y): final.
    read_R2<3>(a2, b2, aA01, aA23, bB01, bB23);
    LGKM(6);
    mfma8<0, 0>(acc, aY, bY);
    LGKM(0);
    mfma8<4, 0>(acc, a2, bY);
    mfma8<0, 2>(acc, aY, b2);
    mfma8<4, 2>(acc, a2, b2);

    // ---- epilogue: 16x16 C/D layout col=lane&15, row=(lane>>4)*4+reg ----
    int orow0 = brow + wr * 128 + fq * 4;
    int ocol0 = bcol + wc * 64 + fr;
#pragma unroll
    for (int n = 0; n < 4; ++n) {
        int col = ocol0 + n * 16;
        float bval = bias[col];
#pragma unroll
        for (int m = 0; m < 8; ++m) {
            int row = orow0 + m * 16;
            float* cp = C + (int64_t)row * N_DIM + col;
#pragma unroll
            for (int j = 0; j < 4; ++j) {
                cp[(int64_t)j * N_DIM] = acc[m][n][j] + bval;
            }
        }
    }
}

extern "C" void kernel_launch(void* const* d_in, const int* in_sizes, int n_in,
                              void* d_out, int out_size, void* d_ws, size_t ws_size,
                              hipStream_t stream) {
    const float* x      = (const float*)d_in[0];
    const int* ci       = (const int*)d_in[1];
    const int* wp       = (const int*)d_in[2];
    const float* scales = (const float*)d_in[3];
    const float* bias   = (const float*)d_in[4];
    float* out          = (float*)d_out;

    const size_t wT_bytes = (size_t)N_DIM * K_DIM * 2;
    unsigned short* wT = (unsigned short*)d_ws;
    unsigned short* xg = wT + (size_t)N_DIM * K_DIM;

    size_t cap = (ws_size > wT_bytes) ? (ws_size - wT_bytes) : 0;
    int max_rows = (int)(cap / ((size_t)K_DIM * 2));
    int chunk_rows = (max_rows / 256) * 256;
    if (chunk_rows <= 0) chunk_rows = 256;      // best effort
    if (chunk_rows > M_DIM) chunk_rows = M_DIM;

    dequant_w_kernel<<<dim3(N_DIM / 64, K_DIM / 64), 256, 0, stream>>>(wp, scales, wT);

    for (int m0 = 0; m0 < M_DIM; m0 += chunk_rows) {
        int rows = M_DIM - m0 < chunk_rows ? M_DIM - m0 : chunk_rows;
        int pgrid = (int)(((int64_t)rows * K_DIM) / (4 * 256));
        permute_x_kernel<<<pgrid, 256, 0, stream>>>(
            x + (int64_t)m0 * K_DIM, ci, xg);
        int grid = (rows / 256) * (N_DIM / 256);
        gemm_kernel<<<grid, 512, 0, stream>>>(
            xg, wT, bias, out + (int64_t)m0 * N_DIM);
    }
}